// Round 2
// baseline (2688.038 us; speedup 1.0000x reference)
//
#include <hip/hip_runtime.h>
#include <hip/hip_bf16.h>

// Problem dims
#define BB   32      // batch
#define NN   98      // image regions
#define EE   2048    // img feature dim
#define HH   512     // hidden
#define VV   10000   // vocab
#define TT   60      // timesteps (T_CAP-1)
#define TCAP 61

typedef unsigned short u16;
typedef __attribute__((ext_vector_type(8))) short bh8;
typedef __attribute__((ext_vector_type(4))) float f32x4;

__device__ __forceinline__ float bsf(unsigned s) {
    union { unsigned u; float f; } w; w.u = s << 16; return w.f;
}
__device__ __forceinline__ u16 f2bu(float f) {
    union { float f; unsigned u; } v; v.f = f;
    unsigned u = v.u;
    u = u + 0x7fffu + ((u >> 16) & 1u);   // RNE
    return (u16)(u >> 16);
}
__device__ __forceinline__ bh8 ld8(const u16* p) {
    return *reinterpret_cast<const bh8*>(p);
}
__device__ __forceinline__ float sigm(float x) {
    return __builtin_amdgcn_rcpf(1.0f + exp2f(-1.4426950408889634f * x));
}
__device__ __forceinline__ float tanh_(float x) {
    return 1.0f - 2.0f * __builtin_amdgcn_rcpf(1.0f + exp2f(2.885390081777927f * x));
}

// ---------------- k_conv: fp32 -> bf16 elementwise (n multiple of 1024) -------
__global__ __launch_bounds__(256) void k_conv(
    const float* __restrict__ src, u16* __restrict__ dst)
{
    int i = blockIdx.x * 256 + threadIdx.x;
    float4 v = reinterpret_cast<const float4*>(src)[i];
    ushort4 o;
    o.x = f2bu(v.x); o.y = f2bu(v.y); o.z = f2bu(v.z); o.w = f2bu(v.w);
    reinterpret_cast<ushort4*>(dst)[i] = o;
}

// ---------------- init1: avg features (fp32) + scaled embedding gather --------
__global__ __launch_bounds__(256) void k_init1(
    const float* __restrict__ img, const int* __restrict__ caps,
    const float* __restrict__ emb, u16* __restrict__ avg_bf, u16* __restrict__ emb_all)
{
    int bid = blockIdx.x, tid = threadIdx.x;
    if (bid < 256) {
        int b = bid >> 3, et = bid & 7;
        int ec = et * 256 + tid;
        const float* p = img + (size_t)(b * NN) * EE + ec;
        float s = 0.f;
        for (int n = 0; n < NN; ++n) s += p[(size_t)n * EE];
        avg_bf[b * EE + ec] = f2bu(s * (1.0f / 98.0f));
    } else {
        int eb = bid - 256;                  // 240 blocks x 8 rows = 1920 rows
        for (int r8 = 0; r8 < 8; ++r8) {
            int row = eb * 8 + r8;           // row = t*32 + b
            int t = row >> 5, b = row & 31;
            int cap = caps[b * TCAP + t];
            const float* src = emb + (size_t)cap * HH;
            u16* dst = emb_all + (size_t)row * HH;
            for (int c = tid; c < HH; c += 256)
                dst[c] = f2bu(src[c] * 22.627416997969522f);  // sqrt(512)
        }
    }
}

// ---------------- init2: h0 = tanh(avg@W_init_h.T+b), c0 likewise (MFMA) ------
__global__ __launch_bounds__(256) void k_init2(
    const u16* __restrict__ avg_bf,
    const u16* __restrict__ Wh_bf, const float* __restrict__ b_h,
    const u16* __restrict__ Wc_bf, const float* __restrict__ b_c,
    u16* __restrict__ h_all, float* __restrict__ c_ws)
{
    __shared__ float red[4][2][64][4];
    int ot = blockIdx.x, tid = threadIdx.x;       // 64 blocks x 16 outputs (1024 total)
    int w = tid >> 6, lane = tid & 63, quad = lane >> 4, l16 = lane & 15;
    int o = ot * 16 + l16;
    const u16* wrow = (o < HH) ? (Wh_bf + (size_t)o * EE) : (Wc_bf + (size_t)(o - HH) * EE);
    f32x4 acc[2]; acc[0] = {0,0,0,0}; acc[1] = {0,0,0,0};
    for (int c = w * 16; c < w * 16 + 16; ++c) {
        int k = c * 32 + quad * 8;
        bh8 b8 = ld8(wrow + k);
        for (int mt = 0; mt < 2; ++mt) {
            bh8 a8 = ld8(avg_bf + (size_t)(mt * 16 + l16) * EE + k);
            acc[mt] = __builtin_amdgcn_mfma_f32_16x16x32_bf16(a8, b8, acc[mt], 0, 0, 0);
        }
    }
    for (int mt = 0; mt < 2; ++mt)
        for (int r = 0; r < 4; ++r) red[w][mt][lane][r] = acc[mt][r];
    __syncthreads();
    for (int idx = tid; idx < 512; idx += 256) {
        int mg = idx >> 4, nn2 = idx & 15;
        int mt = mg >> 4, m = mg & 15;
        int sl = nn2 + 16 * (m >> 2), rg = m & 3;
        float v = red[0][mt][sl][rg] + red[1][mt][sl][rg] + red[2][mt][sl][rg] + red[3][mt][sl][rg];
        int oo = ot * 16 + nn2, b = mg;
        if (oo < HH)
            h_all[(size_t)b * HH + oo] = f2bu(tanh_(v + b_h[oo]));     // h_all[0]
        else
            c_ws[b * HH + (oo - HH)] = tanh_(v + b_c[oo - HH]);
    }
}

// ---------------- Ws = img @ W_att.T + b_att (MFMA, one-shot) -----------------
__global__ __launch_bounds__(256) void k_ws(
    const u16* __restrict__ img_bf, const u16* __restrict__ Watt_bf,
    const float* __restrict__ b_att, u16* __restrict__ Ws_bf)
{
    int bid = blockIdx.x, tid = threadIdx.x;      // 49 mt x 16 nt = 784 blocks
    int mt = bid >> 4, nt = bid & 15;
    int w = tid >> 6, lane = tid & 63, quad = lane >> 4, l16 = lane & 15;
    int rowA = mt * 64 + w * 16 + l16;            // bn index < 3136
    f32x4 acc[2]; acc[0] = {0,0,0,0}; acc[1] = {0,0,0,0};
    const u16* arow = img_bf + (size_t)rowA * EE;
    for (int c = 0; c < 64; ++c) {
        int k = c * 32 + quad * 8;
        bh8 a8 = ld8(arow + k);
        for (int s = 0; s < 2; ++s) {
            bh8 b8 = ld8(Watt_bf + (size_t)(nt * 32 + s * 16 + l16) * EE + k);
            acc[s] = __builtin_amdgcn_mfma_f32_16x16x32_bf16(a8, b8, acc[s], 0, 0, 0);
        }
    }
    for (int s = 0; s < 2; ++s)
        for (int r = 0; r < 4; ++r) {
            int m = quad * 4 + r;
            int row = mt * 64 + w * 16 + m;
            int col = nt * 32 + s * 16 + l16;
            Ws_bf[(size_t)row * HH + col] = f2bu(acc[s][r] + b_att[col]);
        }
}

// ---------------- k_c: Wu_h = h@W_U.T + b_U ; gate = sigm(h@W_fb.T + b_fb) ----
__global__ __launch_bounds__(256) void k_c(
    const u16* __restrict__ h_all, int tIn,
    const u16* __restrict__ WU_bf, const float* __restrict__ b_U,
    const u16* __restrict__ Wfb_bf, const float* __restrict__ b_fb,
    float* __restrict__ Wu_ws, float* __restrict__ gate_ws)
{
    __shared__ float red[4][2][64][4];
    int ot = blockIdx.x, tid = threadIdx.x;       // 160 blocks x 16 outs (2560 total)
    int w = tid >> 6, lane = tid & 63, quad = lane >> 4, l16 = lane & 15;
    int o = ot * 16 + l16;
    const u16* wrow = (o < HH) ? (WU_bf + (size_t)o * HH) : (Wfb_bf + (size_t)(o - HH) * HH);
    const u16* hbase = h_all + (size_t)tIn * BB * HH;
    f32x4 acc[2]; acc[0] = {0,0,0,0}; acc[1] = {0,0,0,0};
    for (int c = w * 4; c < w * 4 + 4; ++c) {
        int k = c * 32 + quad * 8;
        bh8 b8 = ld8(wrow + k);
        for (int mt = 0; mt < 2; ++mt) {
            bh8 a8 = ld8(hbase + (size_t)(mt * 16 + l16) * HH + k);
            acc[mt] = __builtin_amdgcn_mfma_f32_16x16x32_bf16(a8, b8, acc[mt], 0, 0, 0);
        }
    }
    for (int mt = 0; mt < 2; ++mt)
        for (int r = 0; r < 4; ++r) red[w][mt][lane][r] = acc[mt][r];
    __syncthreads();
    for (int idx = tid; idx < 512; idx += 256) {
        int mg = idx >> 4, nn2 = idx & 15;
        int mt = mg >> 4, m = mg & 15;
        int sl = nn2 + 16 * (m >> 2), rg = m & 3;
        float v = red[0][mt][sl][rg] + red[1][mt][sl][rg] + red[2][mt][sl][rg] + red[3][mt][sl][rg];
        int oo = ot * 16 + nn2, b = mg;
        if (oo < HH)
            Wu_ws[b * HH + oo] = v + b_U[oo];
        else
            gate_ws[b * EE + (oo - HH)] = sigm(v + b_fb[oo - HH]);
    }
}

// ---------------- k_a: e = Wv.tanh(Ws+Wu_h)+bv ; softmax ; xctx = gate*ctx ----
__global__ __launch_bounds__(256) void k_a(
    const float* __restrict__ img, const u16* __restrict__ Ws_bf,
    const float* __restrict__ Wu_ws, const float* __restrict__ gate_ws,
    const float* __restrict__ W_v, const float* __restrict__ b_v,
    u16* __restrict__ xctx)
{
    __shared__ float e_sh[NN];
    __shared__ float a_sh[NN];
    int bid = blockIdx.x, tid = threadIdx.x;      // 128 blocks = 32 b x 4 etiles(512)
    int b = bid >> 2, et = bid & 3;
    int w = tid >> 6, lane = tid & 63;
    // stage 1: e[b,n] (each wave a strided subset of n; 64-lane dot over H)
    float wu[8], wv[8];
    {
        const float* wup = Wu_ws + b * HH + lane * 8;
        const float* wvp = W_v + lane * 8;
        #pragma unroll
        for (int j = 0; j < 8; ++j) { wu[j] = wup[j]; wv[j] = wvp[j]; }
    }
    for (int n = w; n < NN; n += 4) {
        bh8 ws8 = ld8(Ws_bf + (size_t)(b * NN + n) * HH + lane * 8);
        float acc = 0.f;
        #pragma unroll
        for (int j = 0; j < 8; ++j) acc += wv[j] * tanh_(bsf((u16)ws8[j]) + wu[j]);
        #pragma unroll
        for (int off = 32; off > 0; off >>= 1) acc += __shfl_down(acc, off, 64);
        if (lane == 0) e_sh[n] = acc + b_v[0];
    }
    __syncthreads();
    // stage 2: softmax over n (wave 0)
    if (tid < 64) {
        float e0 = e_sh[tid];
        float e1 = (tid + 64 < NN) ? e_sh[tid + 64] : -1e30f;
        float m = fmaxf(e0, e1);
        #pragma unroll
        for (int off = 32; off > 0; off >>= 1) m = fmaxf(m, __shfl_xor(m, off, 64));
        const float L2E = 1.4426950408889634f;
        float x0 = exp2f((e0 - m) * L2E);
        float x1 = (tid + 64 < NN) ? exp2f((e1 - m) * L2E) : 0.f;
        float s = x0 + x1;
        #pragma unroll
        for (int off = 32; off > 0; off >>= 1) s += __shfl_xor(s, off, 64);
        float inv = __builtin_amdgcn_rcpf(s);
        a_sh[tid] = x0 * inv;
        if (tid + 64 < NN) a_sh[tid + 64] = x1 * inv;
    }
    __syncthreads();
    // stage 3: context over this block's 512 e-columns (2 per thread), then gate*ctx
    int ec = et * 512 + tid * 2;
    const float* ip = img + (size_t)b * NN * EE + ec;
    float c0 = 0.f, c1 = 0.f;
    for (int n = 0; n < NN; ++n) {
        float2 u = *reinterpret_cast<const float2*>(ip + (size_t)n * EE);
        float a = a_sh[n];
        c0 = fmaf(a, u.x, c0); c1 = fmaf(a, u.y, c1);
    }
    float g0 = gate_ws[b * EE + ec], g1 = gate_ws[b * EE + ec + 1];
    unsigned outw = ((unsigned)f2bu(g1 * c1) << 16) | (unsigned)f2bu(g0 * c0);
    *reinterpret_cast<unsigned*>(xctx + (size_t)b * EE + ec) = outw;
}

// ---------------- k_b: gates GEMM (MFMA, K=3072 concat) + LSTM update ---------
__global__ __launch_bounds__(256) void k_b(
    int t,
    const u16* __restrict__ emb_all, const u16* __restrict__ xctx,
    u16* h_all,                                    // read [t], write [t+1] (aliased)
    const u16* __restrict__ Wih_bf, const float* __restrict__ b_ih,
    const u16* __restrict__ Whh_bf, const float* __restrict__ b_hh,
    float* __restrict__ c_ws)
{
    __shared__ float red[4][64][4];
    __shared__ float gsh[16][16];
    int bid = blockIdx.x, tid = threadIdx.x;       // 256 blocks = 2 mt x 128 kt
    int kt = bid & 127, mt = bid >> 7;
    int w = tid >> 6, lane = tid & 63, quad = lane >> 4, l16 = lane & 15;
    int brow = mt * 16 + l16;
    int j = kt * 4 + (l16 & 3) + HH * (l16 >> 2);  // gate row: k + 512*gate
    const u16* embrow = emb_all + (size_t)(t * BB + brow) * HH;
    const u16* xrow   = xctx + (size_t)brow * EE;
    const u16* hrow   = h_all + (size_t)(t * BB + brow) * HH;
    const u16* wih    = Wih_bf + (size_t)j * (HH + EE);
    const u16* whh    = Whh_bf + (size_t)j * HH;
    f32x4 acc = {0,0,0,0};
    for (int c = w * 24; c < w * 24 + 24; ++c) {   // waves split K: 96 chunks of 32
        int k = c * 32 + quad * 8;
        bh8 a8, b8;
        if (c < 16)      a8 = ld8(embrow + k);
        else if (c < 80) a8 = ld8(xrow + (k - HH));
        else             a8 = ld8(hrow + (k - HH - EE));
        if (c < 80)      b8 = ld8(wih + k);
        else             b8 = ld8(whh + (k - HH - EE));
        acc = __builtin_amdgcn_mfma_f32_16x16x32_bf16(a8, b8, acc, 0, 0, 0);
    }
    for (int r = 0; r < 4; ++r) red[w][lane][r] = acc[r];
    __syncthreads();
    {
        int m = tid >> 4, nn2 = tid & 15;
        int sl = nn2 + 16 * (m >> 2), rg = m & 3;
        int jj = kt * 4 + (nn2 & 3) + HH * (nn2 >> 2);
        float v = red[0][sl][rg] + red[1][sl][rg] + red[2][sl][rg] + red[3][sl][rg]
                + b_ih[jj] + b_hh[jj];
        gsh[m][nn2] = v;
    }
    __syncthreads();
    if (tid < 64) {
        int m = tid >> 2, i = tid & 3;
        int b = mt * 16 + m, k = kt * 4 + i;
        float gi = gsh[m][i], gf = gsh[m][i + 4], gg = gsh[m][i + 8], go = gsh[m][i + 12];
        float cold = c_ws[b * HH + k];
        float c2 = sigm(gf) * cold + sigm(gi) * tanh_(gg);
        float h2 = sigm(go) * tanh_(c2);
        c_ws[b * HH + k] = c2;
        h_all[(size_t)((t + 1) * BB + b) * HH + k] = f2bu(h2);
    }
}

// ---------------- k_pred: all-step pred = h2 @ W_out.T + b_out (MFMA) ---------
__global__ __launch_bounds__(256) void k_pred(
    const u16* __restrict__ h_all, const u16* __restrict__ Wout_bf,
    const float* __restrict__ b_out, float* __restrict__ out)
{
    int bid = blockIdx.x, tid = threadIdx.x;       // 15 mt(128 rows) x 79 vt(128 v)
    int mt = bid / 79, vt = bid % 79;
    int w = tid >> 6, lane = tid & 63, quad = lane >> 4, l16 = lane & 15;
    f32x4 acc[8][2];
    for (int mi = 0; mi < 8; ++mi) for (int s = 0; s < 2; ++s) acc[mi][s] = {0,0,0,0};
    int nact[2]; int vbase[2];
    for (int s = 0; s < 2; ++s) {
        int ntg = vt * 8 + 2 * w + s;               // 625 total 16-wide v-tiles
        nact[s] = (ntg < 625);
        vbase[s] = ntg * 16;
    }
    for (int c = 0; c < 16; ++c) {
        int k = c * 32 + quad * 8;
        bh8 b8[2];
        for (int s = 0; s < 2; ++s) if (nact[s])
            b8[s] = ld8(Wout_bf + (size_t)(vbase[s] + l16) * HH + k);
        for (int mi = 0; mi < 8; ++mi) {
            int row = 32 + mt * 128 + mi * 16 + l16;   // h2 rows (skip h0 block)
            bh8 a8 = ld8(h_all + (size_t)row * HH + k);
            for (int s = 0; s < 2; ++s) if (nact[s])
                acc[mi][s] = __builtin_amdgcn_mfma_f32_16x16x32_bf16(a8, b8[s], acc[mi][s], 0, 0, 0);
        }
    }
    for (int s = 0; s < 2; ++s) if (nact[s]) {
        int v = vbase[s] + l16;
        float bo = b_out[v];
        for (int mi = 0; mi < 8; ++mi)
            for (int r = 0; r < 4; ++r) {
                int row = 32 + mt * 128 + mi * 16 + quad * 4 + r;
                int tt = (row >> 5) - 1, b = row & 31;
                out[(size_t)(b * TT + tt) * VV + v] = acc[mi][s][r] + bo;
            }
    }
}

extern "C" void kernel_launch(void* const* d_in, const int* in_sizes, int n_in,
                              void* d_out, int out_size, void* d_ws, size_t ws_size,
                              hipStream_t stream)
{
    const float* img      = (const float*)d_in[0];
    const int*   caps     = (const int*)d_in[1];
    const float* emb      = (const float*)d_in[2];
    const float* W_init_h = (const float*)d_in[3];
    const float* b_init_h = (const float*)d_in[4];
    const float* W_init_c = (const float*)d_in[5];
    const float* b_init_c = (const float*)d_in[6];
    const float* W_U      = (const float*)d_in[7];
    const float* b_U      = (const float*)d_in[8];
    const float* W_att    = (const float*)d_in[9];
    const float* b_att    = (const float*)d_in[10];
    const float* W_v      = (const float*)d_in[11];
    const float* b_v      = (const float*)d_in[12];
    const float* W_fb     = (const float*)d_in[13];
    const float* b_fb     = (const float*)d_in[14];
    const float* W_ih     = (const float*)d_in[15];
    const float* b_ih     = (const float*)d_in[16];
    const float* W_hh     = (const float*)d_in[17];
    const float* b_hh     = (const float*)d_in[18];
    const float* W_out    = (const float*)d_in[19];
    const float* b_out    = (const float*)d_in[20];
    float* out = (float*)d_out;

    char* ws = (char*)d_ws;
    u16*   img_bf  = (u16*)(ws);                    // 6,422,528 el -> 12,845,056 B
    u16*   Watt_bf = (u16*)(ws + 12845056);         // 1,048,576 el ->  2,097,152 B
    u16*   Winh_bf = (u16*)(ws + 14942208);         // 1,048,576 el ->  2,097,152 B
    u16*   Winc_bf = (u16*)(ws + 17039360);         // 1,048,576 el ->  2,097,152 B
    u16*   WU_bf   = (u16*)(ws + 19136512);         //   262,144 el ->    524,288 B
    u16*   Wfb_bf  = (u16*)(ws + 19660800);         // 1,048,576 el ->  2,097,152 B
    u16*   Wih_bf  = (u16*)(ws + 21757952);         // 5,242,880 el -> 10,485,760 B
    u16*   Whh_bf  = (u16*)(ws + 32243712);         // 1,048,576 el ->  2,097,152 B
    u16*   Wout_bf = (u16*)(ws + 34340864);         // 5,120,000 el -> 10,240,000 B
    u16*   Ws_bf   = (u16*)(ws + 44580864);         // 3136*512     ->  3,211,264 B
    u16*   emb_all = (u16*)(ws + 47792128);         // 1920*512     ->  1,966,080 B
    u16*   h_all   = (u16*)(ws + 49758208);         // 1952*512     ->  1,998,848 B
    u16*   xctx    = (u16*)(ws + 51757056);         // 32*2048      ->    131,072 B
    u16*   avg_bf  = (u16*)(ws + 51888128);         // 32*2048      ->    131,072 B
    float* c_ws    = (float*)(ws + 52019200);       // 32*512*4     ->     65,536 B
    float* Wu_ws   = (float*)(ws + 52084736);       // 32*512*4     ->     65,536 B
    float* gate_ws = (float*)(ws + 52150272);       // 32*2048*4    ->    262,144 B
    // total ws usage: 52,412,416 bytes

    // fp32 -> bf16 conversions (counts all multiples of 1024; grid = n/1024)
    k_conv<<<6272, 256, 0, stream>>>(img,      img_bf);
    k_conv<<<1024, 256, 0, stream>>>(W_att,    Watt_bf);
    k_conv<<<1024, 256, 0, stream>>>(W_init_h, Winh_bf);
    k_conv<<<1024, 256, 0, stream>>>(W_init_c, Winc_bf);
    k_conv<<< 256, 256, 0, stream>>>(W_U,      WU_bf);
    k_conv<<<1024, 256, 0, stream>>>(W_fb,     Wfb_bf);
    k_conv<<<5120, 256, 0, stream>>>(W_ih,     Wih_bf);
    k_conv<<<1024, 256, 0, stream>>>(W_hh,     Whh_bf);
    k_conv<<<5000, 256, 0, stream>>>(W_out,    Wout_bf);

    k_init1<<<496, 256, 0, stream>>>(img, caps, emb, avg_bf, emb_all);
    k_init2<<<64, 256, 0, stream>>>(avg_bf, Winh_bf, b_init_h, Winc_bf, b_init_c, h_all, c_ws);
    k_ws<<<784, 256, 0, stream>>>(img_bf, Watt_bf, b_att, Ws_bf);
    k_c<<<160, 256, 0, stream>>>(h_all, 0, WU_bf, b_U, Wfb_bf, b_fb, Wu_ws, gate_ws);
    for (int t = 0; t < TT; ++t) {
        k_a<<<128, 256, 0, stream>>>(img, Ws_bf, Wu_ws, gate_ws, W_v, b_v, xctx);
        k_b<<<256, 256, 0, stream>>>(t, emb_all, xctx, h_all, Wih_bf, b_ih, Whh_bf, b_hh, c_ws);
        if (t < TT - 1)
            k_c<<<160, 256, 0, stream>>>(h_all, t + 1, WU_bf, b_U, Wfb_bf, b_fb, Wu_ws, gate_ws);
    }
    k_pred<<<1185, 256, 0, stream>>>(h_all, Wout_bf, b_out, out);
}